// Round 5
// baseline (354.922 us; speedup 1.0000x reference)
//
#include <hip/hip_runtime.h>

// ============================================================================
// R5: break the store->load vmcnt serialization in wo. gfx9 has ONE in-order
// vmcnt for loads AND stores; previous versions ended each strip with 16
// W-stores, and the next strip's first K-load use forced s_waitcnt vmcnt(0)
// -> full store drain on the critical path every strip (explains R3's clean
// +26us compute delta: phases are additive). Now: next-strip h0 K-frags are
// prefetched into registers BEFORE this strip's stores are issued; h1-K and
// Vt are streamed in small groups. No wait needs vmcnt(0) while the current
// strip's stores are in flight -> stores drain under the next strip's MFMA.
// prep / lsum / epilogue unchanged from R2.
// ============================================================================

#define SQ 4096
#define DD 64
#define NB 4
#define NEL (NB*SQ*DD)   // 1,048,576 elements per tensor

typedef __attribute__((ext_vector_type(4))) float f32x4;
typedef __attribute__((ext_vector_type(8))) __bf16 bf16x8;

__device__ __forceinline__ unsigned short f2bf(float f) {
  unsigned int u = __builtin_bit_cast(unsigned int, f);
  u = (u + 0x7FFFu + ((u >> 16) & 1u)) >> 16;   // RNE
  return (unsigned short)u;
}

__device__ __forceinline__ bf16x8 ldfrag(const unsigned short* p) {
  uint4 u = *(const uint4*)p;
  return __builtin_bit_cast(bf16x8, u);
}

// pack 8 f32 -> bf16x8; native casts emit v_cvt_pk_bf16_f32
__device__ __forceinline__ bf16x8 pack_bf8(f32x4 a, f32x4 b) {
  bf16x8 r;
  r[0] = (__bf16)a[0]; r[1] = (__bf16)a[1]; r[2] = (__bf16)a[2]; r[3] = (__bf16)a[3];
  r[4] = (__bf16)b[0]; r[5] = (__bf16)b[1]; r[6] = (__bf16)b[2]; r[7] = (__bf16)b[3];
  return r;
}

// ---------------- prep: Q,K -> bf16 ; V -> bf16 transposed [D][S] ----------------
__global__ __launch_bounds__(256) void prep_kernel(
    const float* __restrict__ q, const float* __restrict__ k,
    const float* __restrict__ v, unsigned short* __restrict__ ws)
{
  unsigned short* qbf = ws;
  unsigned short* kbf = ws + (size_t)NEL;
  unsigned short* vt  = ws + 2*(size_t)NEL;
  const int bid = blockIdx.x;
  const int tid = threadIdx.x;
  if (bid < 1024) {
    const float* src = (bid < 512) ? q : k;
    unsigned short* dst = (bid < 512) ? qbf : kbf;
    const int base = (bid & 511) * 512 + tid;
#pragma unroll
    for (int i = 0; i < 2; ++i) {
      int idx = base + i * 256;
      float4 f = ((const float4*)src)[idx];
      ushort4 o;
      o.x = f2bf(f.x); o.y = f2bf(f.y); o.z = f2bf(f.z); o.w = f2bf(f.w);
      ((ushort4*)dst)[idx] = o;
    }
  } else {
    // transpose V: one block per (batch, 64-row s-tile)
    __shared__ unsigned short tile[64][66];
    const int t  = bid - 1024;
    const int bb = t >> 6;
    const int st = t & 63;
    const float* vb = v + (size_t)bb * SQ * DD + (size_t)st * 64 * DD;
    const int r  = tid >> 4;
    const int c4 = tid & 15;
#pragma unroll
    for (int j = 0; j < 4; ++j) {
      int row = r + j * 16;
      float4 f = ((const float4*)(vb + (size_t)row * DD))[c4];
      tile[row][c4 * 4 + 0] = f2bf(f.x);
      tile[row][c4 * 4 + 1] = f2bf(f.y);
      tile[row][c4 * 4 + 2] = f2bf(f.z);
      tile[row][c4 * 4 + 3] = f2bf(f.w);
    }
    __syncthreads();
    unsigned short* vtb = vt + (size_t)bb * DD * SQ;
#pragma unroll
    for (int j = 0; j < 4; ++j) {
      int d   = r + j * 16;
      int s0l = c4 * 4;
      ushort4 o;
      o.x = tile[s0l + 0][d];
      o.y = tile[s0l + 1][d];
      o.z = tile[s0l + 2][d];
      o.w = tile[s0l + 3][d];
      ((ushort4*)(vtb + (size_t)d * SQ + st * 64))[c4] = o;
    }
  }
}

// ---------------- kernel 1: softmax denominators -> li2 = -log2(sum) ----------------
__global__ __launch_bounds__(512, 6) void lsum_kernel(
    const unsigned short* __restrict__ qbf,
    const unsigned short* __restrict__ kbf,
    float* __restrict__ li2_g)
{
  __shared__ float lred[8][4][4];
  const int tid  = threadIdx.x;
  const int wave = tid >> 6;
  const int lane = tid & 63;
  const int l16  = lane & 15;
  const int quad = lane >> 4;

  const int bidx = blockIdx.x;
  const int b    = bidx & 3;          // XCD x sees only batch x&3
  const int qt   = 255 - (bidx >> 2); // heavy first

  const unsigned short* Qb = qbf + (size_t)b * SQ * DD;
  const unsigned short* Kb = kbf + (size_t)b * SQ * DD;
  const int q0    = qt * 16;
  const int rowg0 = q0 + quad * 4;

  bf16x8 aQ0, aQ1;
  {
    const unsigned short* qrow = Qb + (size_t)(q0 + l16) * DD + quad * 8;
    aQ0 = ldfrag(qrow);
    aQ1 = ldfrag(qrow + 32);
  }

  const int nkt = (qt >> 2) + 1;
  const float SC = 0.125f * 1.4426950408889634f;
  const f32x4 zf = {0.f, 0.f, 0.f, 0.f};

  float lsum[4] = {0.f, 0.f, 0.f, 0.f};
  for (int kt = wave; kt < nkt; kt += 8) {
    const int k0 = kt * 64;
    f32x4 acc[4] = {zf, zf, zf, zf};
#pragma unroll
    for (int ct = 0; ct < 4; ++ct) {
      const unsigned short* krow = Kb + (size_t)(k0 + ct * 16 + l16) * DD + quad * 8;
      bf16x8 b0 = ldfrag(krow);
      bf16x8 b1 = ldfrag(krow + 32);
      acc[ct] = __builtin_amdgcn_mfma_f32_16x16x32_bf16(aQ0, b0, acc[ct], 0, 0, 0);
      acc[ct] = __builtin_amdgcn_mfma_f32_16x16x32_bf16(aQ1, b1, acc[ct], 0, 0, 0);
    }
#pragma unroll
    for (int ct = 0; ct < 4; ++ct) {
      const int colg = k0 + ct * 16 + l16;
#pragma unroll
      for (int r = 0; r < 4; ++r) {
        float tt = (colg <= rowg0 + r) ? acc[ct][r] * SC : -1e30f;
        lsum[r] += __builtin_amdgcn_exp2f(tt);
      }
    }
  }
#pragma unroll
  for (int r = 0; r < 4; ++r) {
    float v = lsum[r];
    v += __shfl_xor(v, 1);
    v += __shfl_xor(v, 2);
    v += __shfl_xor(v, 4);
    v += __shfl_xor(v, 8);
    lsum[r] = v;
  }
  if (l16 == 0) {
#pragma unroll
    for (int r = 0; r < 4; ++r) lred[wave][quad][r] = lsum[r];
  }
  __syncthreads();
  if (tid < 16) {
    float s = 0.f;
#pragma unroll
    for (int w = 0; w < 8; ++w) s += lred[w][tid >> 2][tid & 3];
    li2_g[(size_t)b * SQ + q0 + tid] = -__builtin_amdgcn_logf(s);  // -log2(sum)
  }
}

// ---------------- kernel 2: pipelined P -> W store + P*V -> O ----------------
// Per-wave 128-col strips. Next strip's h0 K-frags prefetched before this
// strip's W-stores are issued -> no vmcnt(0) while stores in flight.
__global__ __launch_bounds__(512, 4) void wo_kernel(
    const unsigned short* __restrict__ qbf,
    const unsigned short* __restrict__ kbf,
    const unsigned short* __restrict__ vtp,
    const float* __restrict__ li2_g,
    float* __restrict__ out_vec,
    float* __restrict__ out_w)
{
  // per-wave P f32 staging [16][132]; aliased post-loop as the 16x64 partial-O
  // buffer for the cross-wave combine.
  __shared__ __align__(16) float pt[8][16][132];

  const int tid  = threadIdx.x;
  const int wave = tid >> 6;
  const int lane = tid & 63;
  const int l16  = lane & 15;
  const int quad = lane >> 4;
  const int half = lane >> 5;       // 0 | 1
  const int c32  = lane & 31;

  const int bidx = blockIdx.x;
  const int b    = bidx & 3;
  const int qt   = 255 - (bidx >> 2);

  const unsigned short* Qb = qbf + (size_t)b * SQ * DD;
  const unsigned short* Kb = kbf + (size_t)b * SQ * DD;
  const unsigned short* Vt = vtp + (size_t)b * DD * SQ;  // [D][S]
  float* Wb = out_w  + (size_t)b * SQ * SQ;
  float* Ob = out_vec + (size_t)b * SQ * DD;

  const int q0    = qt * 16;
  const int rowg0 = q0 + quad * 4;

  bf16x8 aQ0, aQ1;
  {
    const unsigned short* qrow = Qb + (size_t)(q0 + l16) * DD + quad * 8;
    aQ0 = ldfrag(qrow);
    aQ1 = ldfrag(qrow + 32);
  }

  float li2[4];
#pragma unroll
  for (int r = 0; r < 4; ++r)
    li2[r] = li2_g[(size_t)b * SQ + rowg0 + r];   // broadcast load

  const int nkt = (qt >> 2) + 1;
  const int nst = (nkt + 1) >> 1;                 // 128-col strips
  const float SC = 0.125f * 1.4426950408889634f;
  const f32x4 zf = {0.f, 0.f, 0.f, 0.f};
  f32x4 accO[4] = {zf, zf, zf, zf};

  // h0 K-fragment prefetch registers (32 VGPR, carried across strips)
  bf16x8 kpre[8];
  if (wave < nst) {
#pragma unroll
    for (int ct = 0; ct < 4; ++ct) {
      const unsigned short* krow =
          Kb + (size_t)(wave * 128 + ct * 16 + l16) * DD + quad * 8;
      kpre[2 * ct]     = ldfrag(krow);
      kpre[2 * ct + 1] = ldfrag(krow + 32);
    }
  }

  for (int st = wave; st < nst; st += 8) {
    const int k0c = st * 128;

    // ---- h0: MFMA from prefetched regs (wait leaves prior stores in flight) ----
    f32x4 acc[4] = {zf, zf, zf, zf};
#pragma unroll
    for (int ct = 0; ct < 4; ++ct) {
      acc[ct] = __builtin_amdgcn_mfma_f32_16x16x32_bf16(aQ0, kpre[2 * ct],     acc[ct], 0, 0, 0);
      acc[ct] = __builtin_amdgcn_mfma_f32_16x16x32_bf16(aQ1, kpre[2 * ct + 1], acc[ct], 0, 0, 0);
    }
#pragma unroll
    for (int ct = 0; ct < 4; ++ct) {
      const int colg = k0c + ct * 16 + l16;
#pragma unroll
      for (int r = 0; r < 4; ++r) {
        float tt = (colg <= rowg0 + r) ? __builtin_fmaf(acc[ct][r], SC, li2[r])
                                       : -1e30f;
        pt[wave][quad * 4 + r][ct * 16 + l16] = __builtin_amdgcn_exp2f(tt);
      }
    }

    // ---- h1: streamed per-ct loads + MFMA (low VGPR; first use drains
    //      prev-strip stores AFTER the h0 compute window) ----
    f32x4 acc2[4] = {zf, zf, zf, zf};
#pragma unroll
    for (int ct = 0; ct < 4; ++ct) {
      const unsigned short* krow =
          Kb + (size_t)(k0c + 64 + ct * 16 + l16) * DD + quad * 8;
      bf16x8 b0 = ldfrag(krow);
      bf16x8 b1 = ldfrag(krow + 32);
      acc2[ct] = __builtin_amdgcn_mfma_f32_16x16x32_bf16(aQ0, b0, acc2[ct], 0, 0, 0);
      acc2[ct] = __builtin_amdgcn_mfma_f32_16x16x32_bf16(aQ1, b1, acc2[ct], 0, 0, 0);
    }
#pragma unroll
    for (int ct = 0; ct < 4; ++ct) {
      const int colg = k0c + 64 + ct * 16 + l16;
#pragma unroll
      for (int r = 0; r < 4; ++r) {
        float tt = (colg <= rowg0 + r) ? __builtin_fmaf(acc2[ct][r], SC, li2[r])
                                       : -1e30f;
        pt[wave][quad * 4 + r][64 + ct * 16 + l16] = __builtin_amdgcn_exp2f(tt);
      }
    }

    // ---- PV over 4 K-chunks of 32 (Vt streamed, 16 VGPR per chunk) ----
#pragma unroll
    for (int kk = 0; kk < 4; ++kk) {
      bf16x8 v0 = ldfrag(Vt + (size_t)(0 * 16 + l16) * SQ + k0c + kk * 32 + quad * 8);
      bf16x8 v1 = ldfrag(Vt + (size_t)(1 * 16 + l16) * SQ + k0c + kk * 32 + quad * 8);
      bf16x8 v2 = ldfrag(Vt + (size_t)(2 * 16 + l16) * SQ + k0c + kk * 32 + quad * 8);
      bf16x8 v3 = ldfrag(Vt + (size_t)(3 * 16 + l16) * SQ + k0c + kk * 32 + quad * 8);
      const float* pr = &pt[wave][l16][kk * 32 + quad * 8];
      f32x4 p0 = *(const f32x4*)pr;
      f32x4 p1 = *(const f32x4*)(pr + 4);
      bf16x8 aP = pack_bf8(p0, p1);
      accO[0] = __builtin_amdgcn_mfma_f32_16x16x32_bf16(aP, v0, accO[0], 0, 0, 0);
      accO[1] = __builtin_amdgcn_mfma_f32_16x16x32_bf16(aP, v1, accO[1], 0, 0, 0);
      accO[2] = __builtin_amdgcn_mfma_f32_16x16x32_bf16(aP, v2, accO[2], 0, 0, 0);
      accO[3] = __builtin_amdgcn_mfma_f32_16x16x32_bf16(aP, v3, accO[3], 0, 0, 0);
    }

    // ---- prefetch next strip's h0 K-frags BEFORE issuing stores ----
    if (st + 8 < nst) {
#pragma unroll
      for (int ct = 0; ct < 4; ++ct) {
        const unsigned short* krow =
            Kb + (size_t)((st + 8) * 128 + ct * 16 + l16) * DD + quad * 8;
        kpre[2 * ct]     = ldfrag(krow);
        kpre[2 * ct + 1] = ldfrag(krow + 32);
      }
    }

    // ---- W store LAST: inst i covers rows {2i, 2i+1} x 512B contiguous.
    //      These drain under the NEXT strip's h0 MFMA + exp2. ----
#pragma unroll
    for (int i = 0; i < 8; ++i) {
      const int rr = 2 * i + half;
      f32x4 pv = *(const f32x4*)&pt[wave][rr][c32 * 4];
      *(f32x4*)(Wb + (size_t)(q0 + rr) * SQ + k0c + c32 * 4) = pv;
    }
  }

  // ---- combine partial O across 8 waves (alias each wave's pt region) ----
  float* ow_mine = &pt[wave][0][0];
#pragma unroll
  for (int ct = 0; ct < 4; ++ct)
#pragma unroll
    for (int r = 0; r < 4; ++r)
      ow_mine[(quad * 4 + r) * 64 + ct * 16 + l16] = accO[ct][r];
  __syncthreads();
#pragma unroll
  for (int i = 0; i < 2; ++i) {
    int idx = tid + i * 512;
    int row = idx >> 6, col = idx & 63;
    float s = 0.f;
#pragma unroll
    for (int w = 0; w < 8; ++w) s += pt[w][0][row * 64 + col];
    Ob[(size_t)(q0 + row) * DD + col] = s;
  }

  // ---- zero-fill fully-masked columns [nst*128, S) for the 16 rows ----
  const int zc0 = nst * 128;
  const int nz4 = (SQ - zc0) >> 2;
  if (nz4 > 0) {
    for (int r = 0; r < 16; ++r) {
      f32x4* zp = (f32x4*)(Wb + (size_t)(q0 + r) * SQ + zc0);
      for (int i = tid; i < nz4; i += 512)
        zp[i] = zf;
    }
  }
}

extern "C" void kernel_launch(void* const* d_in, const int* in_sizes, int n_in,
                              void* d_out, int out_size, void* d_ws, size_t ws_size,
                              hipStream_t stream) {
  const float* q = (const float*)d_in[0];
  const float* k = (const float*)d_in[1];
  const float* v = (const float*)d_in[2];
  float* out_vec = (float*)d_out;
  float* out_w   = out_vec + (size_t)NB * SQ * DD;
  unsigned short* ws = (unsigned short*)d_ws;      // 3*NEL*2 = 6 MB bf16 tensors
  float* li2_g = (float*)(ws + 3 * (size_t)NEL);   // +64 KB row normalizers

  hipLaunchKernelGGL(prep_kernel, dim3(1280), dim3(256), 0, stream, q, k, v, ws);
  hipLaunchKernelGGL(lsum_kernel, dim3(1024), dim3(512), 0, stream,
                     ws, ws + (size_t)NEL, li2_g);
  hipLaunchKernelGGL(wo_kernel, dim3(1024), dim3(512), 0, stream,
                     ws, ws + (size_t)NEL, ws + 2 * (size_t)NEL,
                     li2_g, out_vec, out_w);
}

// Round 6
// 312.151 us; speedup vs baseline: 1.1370x; 1.1370x over previous
//
#include <hip/hip_runtime.h>

// ============================================================================
// R6: single-QK fused kernel. Previous structure evaluated QK^T twice (lsum
// kernel + wo recompute; the recompute alone measured 26us via the R3 probe)
// because normalized W needs the full row denominator. Now one kernel per
// 16-row q-tile stashes UNNORMALIZED P' = exp2(s*SC) as bf16 in a 131KB LDS
// buffer (16 x 4104, +8 pad -> row stride 2052 words == 4 mod 32: fragment
// reads 2-way max), reduces row sums across waves, then streams W = P'*inv_l
// with fully-coalesced 1KB stores interleaved per-1024-chunk with PV MFMA
// reading A-frags DIRECTLY from LDS bf16 (no pack). inv_l folds into the O
// epilogue. Deletes: lsum kernel, QK recompute, phase-2 exp2, pack_bf8.
// Cost: 1 block/CU (8 waves). prep unchanged.
// ============================================================================

#define SQ 4096
#define DD 64
#define NB 4
#define NEL (NB*SQ*DD)   // 1,048,576 elements per tensor
#define PSTRIDE 4104     // 16 x 4104 ushort = 131,328 B; 2052 words == 4 mod 32

typedef __attribute__((ext_vector_type(4))) float f32x4;
typedef __attribute__((ext_vector_type(8))) __bf16 bf16x8;

__device__ __forceinline__ unsigned short f2bf(float f) {
  unsigned int u = __builtin_bit_cast(unsigned int, f);
  u = (u + 0x7FFFu + ((u >> 16) & 1u)) >> 16;   // RNE
  return (unsigned short)u;
}

__device__ __forceinline__ bf16x8 ldfrag(const unsigned short* p) {
  uint4 u = *(const uint4*)p;
  return __builtin_bit_cast(bf16x8, u);
}

__device__ __forceinline__ float bf2f(unsigned short u) {
  return __builtin_bit_cast(float, (unsigned int)u << 16);
}

// ---------------- prep: Q,K -> bf16 ; V -> bf16 transposed [D][S] ----------------
__global__ __launch_bounds__(256) void prep_kernel(
    const float* __restrict__ q, const float* __restrict__ k,
    const float* __restrict__ v, unsigned short* __restrict__ ws)
{
  unsigned short* qbf = ws;
  unsigned short* kbf = ws + (size_t)NEL;
  unsigned short* vt  = ws + 2*(size_t)NEL;
  const int bid = blockIdx.x;
  const int tid = threadIdx.x;
  if (bid < 1024) {
    const float* src = (bid < 512) ? q : k;
    unsigned short* dst = (bid < 512) ? qbf : kbf;
    const int base = (bid & 511) * 512 + tid;
#pragma unroll
    for (int i = 0; i < 2; ++i) {
      int idx = base + i * 256;
      float4 f = ((const float4*)src)[idx];
      ushort4 o;
      o.x = f2bf(f.x); o.y = f2bf(f.y); o.z = f2bf(f.z); o.w = f2bf(f.w);
      ((ushort4*)dst)[idx] = o;
    }
  } else {
    // transpose V: one block per (batch, 64-row s-tile)
    __shared__ unsigned short tile[64][66];
    const int t  = bid - 1024;
    const int bb = t >> 6;
    const int st = t & 63;
    const float* vb = v + (size_t)bb * SQ * DD + (size_t)st * 64 * DD;
    const int r  = tid >> 4;
    const int c4 = tid & 15;
#pragma unroll
    for (int j = 0; j < 4; ++j) {
      int row = r + j * 16;
      float4 f = ((const float4*)(vb + (size_t)row * DD))[c4];
      tile[row][c4 * 4 + 0] = f2bf(f.x);
      tile[row][c4 * 4 + 1] = f2bf(f.y);
      tile[row][c4 * 4 + 2] = f2bf(f.z);
      tile[row][c4 * 4 + 3] = f2bf(f.w);
    }
    __syncthreads();
    unsigned short* vtb = vt + (size_t)bb * DD * SQ;
#pragma unroll
    for (int j = 0; j < 4; ++j) {
      int d   = r + j * 16;
      int s0l = c4 * 4;
      ushort4 o;
      o.x = tile[s0l + 0][d];
      o.y = tile[s0l + 1][d];
      o.z = tile[s0l + 2][d];
      o.w = tile[s0l + 3][d];
      ((ushort4*)(vtb + (size_t)d * SQ + st * 64))[c4] = o;
    }
  }
}

// ---------------- fused attention: single QK pass, LDS-resident P' ----------------
__global__ __launch_bounds__(512, 2) void attn_kernel(
    const unsigned short* __restrict__ qbf,
    const unsigned short* __restrict__ kbf,
    const unsigned short* __restrict__ vtp,
    float* __restrict__ out_vec,
    float* __restrict__ out_w)
{
  __shared__ __align__(16) unsigned short Ps[16 * PSTRIDE];  // 131,328 B
  __shared__ float lred[8][4][4];
  __shared__ float inv_l_s[16];

  const int tid  = threadIdx.x;
  const int wave = tid >> 6;
  const int lane = tid & 63;
  const int l16  = lane & 15;
  const int quad = lane >> 4;

  const int bidx = blockIdx.x;
  const int b    = bidx & 3;          // XCD x sees only batch x&3
  const int qt   = 255 - (bidx >> 2); // heavy first

  const unsigned short* Qb = qbf + (size_t)b * SQ * DD;
  const unsigned short* Kb = kbf + (size_t)b * SQ * DD;
  const unsigned short* Vt = vtp + (size_t)b * DD * SQ;  // [D][S]
  float* Wb = out_w  + (size_t)b * SQ * SQ;
  float* Ob = out_vec + (size_t)b * SQ * DD;

  const int q0    = qt * 16;
  const int rowg0 = q0 + quad * 4;

  bf16x8 aQ0, aQ1;
  {
    const unsigned short* qrow = Qb + (size_t)(q0 + l16) * DD + quad * 8;
    aQ0 = ldfrag(qrow);
    aQ1 = ldfrag(qrow + 32);
  }

  const int nkt  = (qt >> 2) + 1;       // causal 64-col k-tiles
  const int nch  = (nkt + 15) >> 4;     // 1024-col chunks (LDS/store granule)
  const int nstp = nch << 3;            // 128-col strips, chunk-padded
  const float SC = 0.125f * 1.4426950408889634f;
  const f32x4 zf = {0.f, 0.f, 0.f, 0.f};

  // ---- phase 1: QK^T once; stash P'=exp2(s*SC) bf16 in LDS; row sums ----
  float lsum[4] = {0.f, 0.f, 0.f, 0.f};
  for (int st = wave; st < nstp; st += 8) {
    const int k0c = st * 128;
    if (k0c <= q0 + 15) {
#pragma unroll
      for (int h = 0; h < 2; ++h) {
        const int k0 = k0c + h * 64;
        f32x4 acc[4] = {zf, zf, zf, zf};
#pragma unroll
        for (int ct = 0; ct < 4; ++ct) {
          const unsigned short* krow = Kb + (size_t)(k0 + ct * 16 + l16) * DD + quad * 8;
          bf16x8 b0 = ldfrag(krow);
          bf16x8 b1 = ldfrag(krow + 32);
          acc[ct] = __builtin_amdgcn_mfma_f32_16x16x32_bf16(aQ0, b0, acc[ct], 0, 0, 0);
          acc[ct] = __builtin_amdgcn_mfma_f32_16x16x32_bf16(aQ1, b1, acc[ct], 0, 0, 0);
        }
#pragma unroll
        for (int ct = 0; ct < 4; ++ct) {
          const int colg = k0 + ct * 16 + l16;
#pragma unroll
          for (int r = 0; r < 4; ++r) {
            float tt = (colg <= rowg0 + r) ? acc[ct][r] * SC : -1e30f;
            float p  = __builtin_amdgcn_exp2f(tt);   // unnormalized, <= ~2^8
            lsum[r] += p;
            Ps[(quad * 4 + r) * PSTRIDE + colg] =
                __builtin_bit_cast(unsigned short, (__bf16)p);
          }
        }
      }
    } else {
      // dead strip inside chunk padding: zero 16x128 region
#pragma unroll
      for (int h = 0; h < 2; ++h)
#pragma unroll
        for (int ct = 0; ct < 4; ++ct)
#pragma unroll
          for (int r = 0; r < 4; ++r)
            Ps[(quad * 4 + r) * PSTRIDE + k0c + h * 64 + ct * 16 + l16] = 0;
    }
  }

  // ---- cross-wave denominator reduction -> inv_l_s[16] ----
#pragma unroll
  for (int r = 0; r < 4; ++r) {
    float v = lsum[r];
    v += __shfl_xor(v, 1);
    v += __shfl_xor(v, 2);
    v += __shfl_xor(v, 4);
    v += __shfl_xor(v, 8);
    lsum[r] = v;
  }
  if (l16 == 0) {
#pragma unroll
    for (int r = 0; r < 4; ++r) lred[wave][quad][r] = lsum[r];
  }
  __syncthreads();
  if (tid < 16) {
    float s = 0.f;
#pragma unroll
    for (int w = 0; w < 8; ++w) s += lred[w][tid >> 2][tid & 3];
    inv_l_s[tid] = 1.0f / s;
  }
  __syncthreads();

  // ---- phase 2: per chunk, stream W rows (coalesced) + PV from LDS bf16 ----
  f32x4 accO[4] = {zf, zf, zf, zf};
  const int r0 = 2 * wave;

  for (int ch = 0; ch < nch; ++ch) {
    const int c0 = ch << 10;
    // W stream: wave owns rows {2w, 2w+1}; 4 insts/row, each 1KB contiguous
#pragma unroll
    for (int rr = 0; rr < 2; ++rr) {
      const int row = r0 + rr;
      const float invr = inv_l_s[row];
      const unsigned short* src = &Ps[row * PSTRIDE + c0];
      float* dst = Wb + (size_t)(q0 + row) * SQ + c0;
#pragma unroll
      for (int g = 0; g < 4; ++g) {
        ushort4 u = *(const ushort4*)(src + g * 256 + lane * 4);
        f32x4 o;
        o[0] = bf2f(u.x) * invr;
        o[1] = bf2f(u.y) * invr;
        o[2] = bf2f(u.z) * invr;
        o[3] = bf2f(u.w) * invr;
        *(f32x4*)(dst + g * 256 + lane * 4) = o;
      }
    }
    // PV over this wave's 128-col strip of the chunk; A-frags straight from LDS
    const int sb = c0 + wave * 128;
    if (sb <= q0 + 15) {
#pragma unroll
      for (int kk = 0; kk < 4; ++kk) {
        const int cb = sb + kk * 32 + quad * 8;
        bf16x8 aP = *(const bf16x8*)(&Ps[l16 * PSTRIDE + cb]);
#pragma unroll
        for (int ct = 0; ct < 4; ++ct) {
          const unsigned short* vrow = Vt + (size_t)(ct * 16 + l16) * SQ + cb;
          bf16x8 bv = ldfrag(vrow);
          accO[ct] = __builtin_amdgcn_mfma_f32_16x16x32_bf16(aP, bv, accO[ct], 0, 0, 0);
        }
      }
    }
  }

  // ---- O combine across waves (alias Ps region; inv_l folded here) ----
  float invq[4];
#pragma unroll
  for (int r = 0; r < 4; ++r) invq[r] = inv_l_s[quad * 4 + r];
  __syncthreads();                      // all Ps reads complete
  float* stag = (float*)Ps;             // 8 waves x 16x64 f32 = 32 KB
  float* ow = stag + wave * 1024;
#pragma unroll
  for (int ct = 0; ct < 4; ++ct)
#pragma unroll
    for (int r = 0; r < 4; ++r)
      ow[(quad * 4 + r) * 64 + ct * 16 + l16] = accO[ct][r] * invq[r];
  __syncthreads();
#pragma unroll
  for (int i = 0; i < 2; ++i) {
    int idx = tid + i * 512;
    int row = idx >> 6, col = idx & 63;
    float s = 0.f;
#pragma unroll
    for (int w = 0; w < 8; ++w) s += stag[w * 1024 + row * 64 + col];
    Ob[(size_t)(q0 + row) * DD + col] = s;
  }

  // ---- zero-fill fully-masked columns [nch*1024, S) for the 16 rows ----
  const int zc0 = nch << 10;
  const int nz4 = (SQ - zc0) >> 2;
  if (nz4 > 0) {
    for (int r = 0; r < 16; ++r) {
      f32x4* zp = (f32x4*)(Wb + (size_t)(q0 + r) * SQ + zc0);
      for (int i = tid; i < nz4; i += 512)
        zp[i] = zf;
    }
  }
}

extern "C" void kernel_launch(void* const* d_in, const int* in_sizes, int n_in,
                              void* d_out, int out_size, void* d_ws, size_t ws_size,
                              hipStream_t stream) {
  const float* q = (const float*)d_in[0];
  const float* k = (const float*)d_in[1];
  const float* v = (const float*)d_in[2];
  float* out_vec = (float*)d_out;
  float* out_w   = out_vec + (size_t)NB * SQ * DD;
  unsigned short* ws = (unsigned short*)d_ws;      // 3*NEL*2 = 6 MB bf16 tensors

  hipLaunchKernelGGL(prep_kernel, dim3(1280), dim3(256), 0, stream, q, k, v, ws);
  hipLaunchKernelGGL(attn_kernel, dim3(1024), dim3(512), 0, stream,
                     ws, ws + (size_t)NEL, ws + 2 * (size_t)NEL,
                     out_vec, out_w);
}

// Round 8
// 311.031 us; speedup vs baseline: 1.1411x; 1.0036x over previous
//
#include <hip/hip_runtime.h>

// ============================================================================
// R8 = R7 resubmission (R7 bench died to container failure, no kernel verdict).
// R6 (fused single-QK, LDS-resident bf16 P') + two phase-1 fixes:
//  1. Swapped QK MFMA operands: mfma(K,Q) instead of mfma(Q,K). Bit-identical
//     math, but the C-layout becomes (row=q-row=l16, cols=4 CONSECUTIVE
//     k-cols per reg) -> the 4 bf16 P' values pack into ONE ds_write_b64
//     (was 4 scalar ds_write_b16): 64 -> 16 LDS write insts per 64-col tile.
//  2. Double-buffered K prefetch: next tile's 8 b128 K-loads issued before
//     current tile's MFMA+exp2+pack -> L2 latency hidden at 2 waves/SIMD.
// Phase 2 (W stream + PV from LDS), prep, epilogue unchanged from R6.
// ============================================================================

#define SQ 4096
#define DD 64
#define NB 4
#define NEL (NB*SQ*DD)   // 1,048,576 elements per tensor
#define PSTRIDE 4104     // ushorts; 16 rows x 4104 x 2B = 131,328 B LDS

typedef __attribute__((ext_vector_type(4))) float f32x4;
typedef __attribute__((ext_vector_type(8))) __bf16 bf16x8;

__device__ __forceinline__ unsigned short f2bf(float f) {
  unsigned int u = __builtin_bit_cast(unsigned int, f);
  u = (u + 0x7FFFu + ((u >> 16) & 1u)) >> 16;   // RNE
  return (unsigned short)u;
}

__device__ __forceinline__ bf16x8 ldfrag(const unsigned short* p) {
  uint4 u = *(const uint4*)p;
  return __builtin_bit_cast(bf16x8, u);
}

__device__ __forceinline__ float bf2f(unsigned short u) {
  return __builtin_bit_cast(float, (unsigned int)u << 16);
}

// ---------------- prep: Q,K -> bf16 ; V -> bf16 transposed [D][S] ----------------
__global__ __launch_bounds__(256) void prep_kernel(
    const float* __restrict__ q, const float* __restrict__ k,
    const float* __restrict__ v, unsigned short* __restrict__ ws)
{
  unsigned short* qbf = ws;
  unsigned short* kbf = ws + (size_t)NEL;
  unsigned short* vt  = ws + 2*(size_t)NEL;
  const int bid = blockIdx.x;
  const int tid = threadIdx.x;
  if (bid < 1024) {
    const float* src = (bid < 512) ? q : k;
    unsigned short* dst = (bid < 512) ? qbf : kbf;
    const int base = (bid & 511) * 512 + tid;
#pragma unroll
    for (int i = 0; i < 2; ++i) {
      int idx = base + i * 256;
      float4 f = ((const float4*)src)[idx];
      ushort4 o;
      o.x = f2bf(f.x); o.y = f2bf(f.y); o.z = f2bf(f.z); o.w = f2bf(f.w);
      ((ushort4*)dst)[idx] = o;
    }
  } else {
    // transpose V: one block per (batch, 64-row s-tile)
    __shared__ unsigned short tile[64][66];
    const int t  = bid - 1024;
    const int bb = t >> 6;
    const int st = t & 63;
    const float* vb = v + (size_t)bb * SQ * DD + (size_t)st * 64 * DD;
    const int r  = tid >> 4;
    const int c4 = tid & 15;
#pragma unroll
    for (int j = 0; j < 4; ++j) {
      int row = r + j * 16;
      float4 f = ((const float4*)(vb + (size_t)row * DD))[c4];
      tile[row][c4 * 4 + 0] = f2bf(f.x);
      tile[row][c4 * 4 + 1] = f2bf(f.y);
      tile[row][c4 * 4 + 2] = f2bf(f.z);
      tile[row][c4 * 4 + 3] = f2bf(f.w);
    }
    __syncthreads();
    unsigned short* vtb = vt + (size_t)bb * DD * SQ;
#pragma unroll
    for (int j = 0; j < 4; ++j) {
      int d   = r + j * 16;
      int s0l = c4 * 4;
      ushort4 o;
      o.x = tile[s0l + 0][d];
      o.y = tile[s0l + 1][d];
      o.z = tile[s0l + 2][d];
      o.w = tile[s0l + 3][d];
      ((ushort4*)(vtb + (size_t)d * SQ + st * 64))[c4] = o;
    }
  }
}

// ---------------- fused attention: single QK pass, LDS-resident P' ----------------
__global__ __launch_bounds__(512, 2) void attn_kernel(
    const unsigned short* __restrict__ qbf,
    const unsigned short* __restrict__ kbf,
    const unsigned short* __restrict__ vtp,
    float* __restrict__ out_vec,
    float* __restrict__ out_w)
{
  __shared__ __align__(16) unsigned short Ps[16 * PSTRIDE];  // 131,328 B
  __shared__ float lredS[8][16];
  __shared__ float inv_l_s[16];

  const int tid  = threadIdx.x;
  const int wave = tid >> 6;
  const int lane = tid & 63;
  const int l16  = lane & 15;
  const int quad = lane >> 4;

  const int bidx = blockIdx.x;
  const int b    = bidx & 3;          // XCD x sees only batch x&3
  const int qt   = 255 - (bidx >> 2); // heavy first

  const unsigned short* Qb = qbf + (size_t)b * SQ * DD;
  const unsigned short* Kb = kbf + (size_t)b * SQ * DD;
  const unsigned short* Vt = vtp + (size_t)b * DD * SQ;  // [D][S]
  float* Wb = out_w  + (size_t)b * SQ * SQ;
  float* Ob = out_vec + (size_t)b * SQ * DD;

  const int q0   = qt * 16;
  const int qrow = q0 + l16;          // this lane's q-row (swapped layout)

  bf16x8 aQ0, aQ1;
  {
    const unsigned short* qrp = Qb + (size_t)(q0 + l16) * DD + quad * 8;
    aQ0 = ldfrag(qrp);
    aQ1 = ldfrag(qrp + 32);
  }

  const int nkt = (qt >> 2) + 1;        // causal 64-col k-tiles
  const int nch = (nkt + 15) >> 4;      // 1024-col chunks (LDS/store granule)
  const int ntp = nch << 4;             // 64-col tiles incl. chunk padding
  const int lastlive = (q0 + 15) >> 6;  // last tile with any unmasked col
  const float SC = 0.125f * 1.4426950408889634f;
  const f32x4 zf = {0.f, 0.f, 0.f, 0.f};

  // ---- phase 1: QK^T once (swapped operands); packed bf16 stash; row sums ----
  float lsum = 0.f;
  bf16x8 ka[8], kb[8];
  {
    int kt = wave;
    if (kt <= lastlive) {
#pragma unroll
      for (int ct = 0; ct < 4; ++ct) {
        const unsigned short* krow =
            Kb + (size_t)(kt * 64 + ct * 16 + l16) * DD + quad * 8;
        ka[2 * ct]     = ldfrag(krow);
        ka[2 * ct + 1] = ldfrag(krow + 32);
      }
    }
    for (; kt < ntp; kt += 8) {
      const int ktn = kt + 8;
      if (ktn <= lastlive) {        // prefetch next tile (wave-uniform branch)
#pragma unroll
        for (int ct = 0; ct < 4; ++ct) {
          const unsigned short* krow =
              Kb + (size_t)(ktn * 64 + ct * 16 + l16) * DD + quad * 8;
          kb[2 * ct]     = ldfrag(krow);
          kb[2 * ct + 1] = ldfrag(krow + 32);
        }
      }
      const int k0 = kt * 64;
      if (kt <= lastlive) {
        f32x4 acc[4] = {zf, zf, zf, zf};
#pragma unroll
        for (int ct = 0; ct < 4; ++ct) {
          acc[ct] = __builtin_amdgcn_mfma_f32_16x16x32_bf16(ka[2 * ct],     aQ0, acc[ct], 0, 0, 0);
          acc[ct] = __builtin_amdgcn_mfma_f32_16x16x32_bf16(ka[2 * ct + 1], aQ1, acc[ct], 0, 0, 0);
        }
        // lane holds q-row=l16, k-cols = k0 + ct*16 + quad*4 + {0..3}
#pragma unroll
        for (int ct = 0; ct < 4; ++ct) {
          const int colb = k0 + ct * 16 + quad * 4;
          float p0 = __builtin_amdgcn_exp2f((colb + 0 <= qrow) ? acc[ct][0] * SC : -1e30f);
          float p1 = __builtin_amdgcn_exp2f((colb + 1 <= qrow) ? acc[ct][1] * SC : -1e30f);
          float p2 = __builtin_amdgcn_exp2f((colb + 2 <= qrow) ? acc[ct][2] * SC : -1e30f);
          float p3 = __builtin_amdgcn_exp2f((colb + 3 <= qrow) ? acc[ct][3] * SC : -1e30f);
          lsum += (p0 + p1) + (p2 + p3);
          ushort4 pk;
          pk.x = __builtin_bit_cast(unsigned short, (__bf16)p0);
          pk.y = __builtin_bit_cast(unsigned short, (__bf16)p1);
          pk.z = __builtin_bit_cast(unsigned short, (__bf16)p2);
          pk.w = __builtin_bit_cast(unsigned short, (__bf16)p3);
          *(ushort4*)&Ps[l16 * PSTRIDE + colb] = pk;   // one ds_write_b64
        }
#pragma unroll
        for (int i = 0; i < 8; ++i) ka[i] = kb[i];
      } else {
        // dead padding tile: packed zero stash
        const ushort4 z4 = {0, 0, 0, 0};
#pragma unroll
        for (int ct = 0; ct < 4; ++ct)
          *(ushort4*)&Ps[l16 * PSTRIDE + k0 + ct * 16 + quad * 4] = z4;
      }
    }
  }

  // ---- cross-wave denominator reduction -> inv_l_s[16] ----
  {
    float v = lsum;
    v += __shfl_xor(v, 16);
    v += __shfl_xor(v, 32);
    if (lane < 16) lredS[wave][lane] = v;
  }
  __syncthreads();
  if (tid < 16) {
    float s = 0.f;
#pragma unroll
    for (int w = 0; w < 8; ++w) s += lredS[w][tid];
    inv_l_s[tid] = 1.0f / s;
  }
  __syncthreads();

  // ---- phase 2: per chunk, stream W rows (coalesced) + PV from LDS bf16 ----
  f32x4 accO[4] = {zf, zf, zf, zf};
  const int r0 = 2 * wave;
  const float invr0 = inv_l_s[r0];
  const float invr1 = inv_l_s[r0 + 1];

  for (int ch = 0; ch < nch; ++ch) {
    const int c0 = ch << 10;
    // W stream: wave owns rows {2w, 2w+1}; 4 insts/row, each 1KB contiguous
#pragma unroll
    for (int rr = 0; rr < 2; ++rr) {
      const int row = r0 + rr;
      const float invr = rr ? invr1 : invr0;
      const unsigned short* src = &Ps[row * PSTRIDE + c0];
      float* dst = Wb + (size_t)(q0 + row) * SQ + c0;
#pragma unroll
      for (int g = 0; g < 4; ++g) {
        ushort4 u = *(const ushort4*)(src + g * 256 + lane * 4);
        f32x4 o;
        o[0] = bf2f(u.x) * invr;
        o[1] = bf2f(u.y) * invr;
        o[2] = bf2f(u.z) * invr;
        o[3] = bf2f(u.w) * invr;
        *(f32x4*)(dst + g * 256 + lane * 4) = o;
      }
    }
    // PV over this wave's 128-col strip of the chunk; A-frags straight from LDS
    const int sb = c0 + wave * 128;
    if (sb <= q0 + 15) {
#pragma unroll
      for (int kk = 0; kk < 4; ++kk) {
        const int cb = sb + kk * 32 + quad * 8;
        bf16x8 aP = *(const bf16x8*)(&Ps[l16 * PSTRIDE + cb]);
#pragma unroll
        for (int ct = 0; ct < 4; ++ct) {
          const unsigned short* vrow = Vt + (size_t)(ct * 16 + l16) * SQ + cb;
          bf16x8 bv = ldfrag(vrow);
          accO[ct] = __builtin_amdgcn_mfma_f32_16x16x32_bf16(aP, bv, accO[ct], 0, 0, 0);
        }
      }
    }
  }

  // ---- O combine across waves (alias Ps region; inv_l folded here) ----
  float invq[4];
#pragma unroll
  for (int r = 0; r < 4; ++r) invq[r] = inv_l_s[quad * 4 + r];
  __syncthreads();                      // all Ps reads complete
  float* stag = (float*)Ps;             // 8 waves x 16x64 f32 = 32 KB
  float* ow = stag + wave * 1024;
#pragma unroll
  for (int ct = 0; ct < 4; ++ct)
#pragma unroll
    for (int r = 0; r < 4; ++r)
      ow[(quad * 4 + r) * 64 + ct * 16 + l16] = accO[ct][r] * invq[r];
  __syncthreads();
#pragma unroll
  for (int i = 0; i < 2; ++i) {
    int idx = tid + i * 512;
    int row = idx >> 6, col = idx & 63;
    float s = 0.f;
#pragma unroll
    for (int w = 0; w < 8; ++w) s += stag[w * 1024 + row * 64 + col];
    Ob[(size_t)(q0 + row) * DD + col] = s;
  }

  // ---- zero-fill fully-masked columns [nch*1024, S) for the 16 rows ----
  const int zc0 = nch << 10;
  const int nz4 = (SQ - zc0) >> 2;
  if (nz4 > 0) {
    for (int r = 0; r < 16; ++r) {
      f32x4* zp = (f32x4*)(Wb + (size_t)(q0 + r) * SQ + zc0);
      for (int i = tid; i < nz4; i += 512)
        zp[i] = zf;
    }
  }
}

extern "C" void kernel_launch(void* const* d_in, const int* in_sizes, int n_in,
                              void* d_out, int out_size, void* d_ws, size_t ws_size,
                              hipStream_t stream) {
  const float* q = (const float*)d_in[0];
  const float* k = (const float*)d_in[1];
  const float* v = (const float*)d_in[2];
  float* out_vec = (float*)d_out;
  float* out_w   = out_vec + (size_t)NB * SQ * DD;
  unsigned short* ws = (unsigned short*)d_ws;      // 3*NEL*2 = 6 MB bf16 tensors

  hipLaunchKernelGGL(prep_kernel, dim3(1280), dim3(256), 0, stream, q, k, v, ws);
  hipLaunchKernelGGL(attn_kernel, dim3(1024), dim3(512), 0, stream,
                     ws, ws + (size_t)NEL, ws + 2 * (size_t)NEL,
                     out_vec, out_w);
}